// Round 1
// baseline (139.090 us; speedup 1.0000x reference)
//
#include <hip/hip_runtime.h>

// EmbeddingFreeContextAttention: B=32, L=512, D=768, fp32.
// out[b,l,k*D+d] = sent[b,l,d] * dot(sent[b,idxs[b,k],:], sent[b,l,:])
// One block per (b,l). 192 threads, one float4 (4 floats) per thread (192*4=768).

constexpr int B = 32;
constexpr int L = 512;
constexpr int D = 768;
constexpr int THREADS = 192;   // 3 waves of 64; 192 float4 per row

__global__ __launch_bounds__(THREADS)
void efca_kernel(const float* __restrict__ sent,
                 const int* __restrict__ idxs,
                 float* __restrict__ out) {
    const int bl = blockIdx.x;          // 0 .. B*L-1
    const int b  = bl >> 9;             // / L (L=512)
    const int l  = bl & (L - 1);
    const int t  = threadIdx.x;         // 0..191

    const float4* __restrict__ row =
        reinterpret_cast<const float4*>(sent + (size_t)(b * L + l) * D);
    const int i0 = idxs[b * 2 + 0];
    const int i1 = idxs[b * 2 + 1];
    const float4* __restrict__ e0 =
        reinterpret_cast<const float4*>(sent + (size_t)(b * L + i0) * D);
    const float4* __restrict__ e1 =
        reinterpret_cast<const float4*>(sent + (size_t)(b * L + i1) * D);

    const float4 r  = row[t];
    const float4 a  = e0[t];
    const float4 c  = e1[t];

    float p0 = r.x * a.x + r.y * a.y + r.z * a.z + r.w * a.w;
    float p1 = r.x * c.x + r.y * c.y + r.z * c.z + r.w * c.w;

    // wave-64 butterfly reduce
    #pragma unroll
    for (int off = 32; off > 0; off >>= 1) {
        p0 += __shfl_down(p0, off, 64);
        p1 += __shfl_down(p1, off, 64);
    }

    __shared__ float s0[3], s1[3];
    __shared__ float fa0, fa1;
    const int wave = t >> 6;
    const int lane = t & 63;
    if (lane == 0) { s0[wave] = p0; s1[wave] = p1; }
    __syncthreads();
    if (t == 0) {
        fa0 = s0[0] + s0[1] + s0[2];
        fa1 = s1[0] + s1[1] + s1[2];
    }
    __syncthreads();
    const float a0 = fa0;
    const float a1 = fa1;

    float4* __restrict__ o =
        reinterpret_cast<float4*>(out + (size_t)(b * L + l) * (2 * D));
    o[t]           = make_float4(r.x * a0, r.y * a0, r.z * a0, r.w * a0);
    o[t + THREADS] = make_float4(r.x * a1, r.y * a1, r.z * a1, r.w * a1);
}

extern "C" void kernel_launch(void* const* d_in, const int* in_sizes, int n_in,
                              void* d_out, int out_size, void* d_ws, size_t ws_size,
                              hipStream_t stream) {
    const float* sent = (const float*)d_in[0];
    const int*   idxs = (const int*)d_in[1];
    float*       out  = (float*)d_out;

    dim3 grid(B * L);
    dim3 block(THREADS);
    efca_kernel<<<grid, block, 0, stream>>>(sent, idxs, out);
}